// Round 4
// baseline (839.818 us; speedup 1.0000x reference)
//
#include <hip/hip_runtime.h>
#include <float.h>

// knnFlow: pc1 [B,3,N] f32, pc2 [B,3,N] f32 -> flow [B,3,N] f32
// Bit-replicates the reference's f32 Gram expansion (absmax 0.0 verified R2/R3):
//   sq = (x*x + y*y) + z*z               (plain rounded ops, no FMA)
//   t0 = x1*x2; t1 = fmaf(y1,y2,t0); t2 = fmaf(z1,z2,t1)
//   d2 = fmaf(t2, -2.0f, sq1+sq2)        (== (sq1+sq2) - 2*gram bit-exactly)
// argmin = lexicographic min over (d2, orig_j): equals np.argmin first-occurrence.
//
// Bucketed exact search: counting-sort pc2 by x into 256 buckets/batch; per query
// walk buckets outward; stop a side when its edge dx^2 > best + MARGIN.
// MARGIN=2e-3 >> 6e-5 worst-case |ref_d2 - true_d2| => ref argmin provably scanned.
// Intra-bucket order is nondeterministic (atomic scatter) but the final lex-min
// over a deterministic candidate SET is order-independent => deterministic output.

#define BATCH 8
#define N     8192
#define NB    256
#define XMINB (-5.12f)
#define BH    (0.04f)
#define INVH  (25.0f)
#define MARGIN (2.0e-3f)

__device__ __forceinline__ int bucketOf(float x) {
    int k = (int)floorf((x - XMINB) * INVH);
    return k < 0 ? 0 : (k > NB - 1 ? NB - 1 : k);
}

// ws layout (bytes):
//  cnt   [2][B][NB]   u32  @ 0         (16384)
//  start [2][B][NB+1] u32  @ 16384     (16448)
//  cursor[2][B][NB]   u32  @ 33024     (16384)
//  s2f4  [B][N] float4     @ 65536     (1048576)   (x,y,z,sq)
//  s2j   [B][N] int        @ 1114112   (262144)
//  s1f4  [B][N] float4     @ 1376256   (1048576)   (x,y,z,sq)
//  s1q   [B][N] int        @ 2424832   (262144)    -> ends 2686976
#define OFF_CNT    0
#define OFF_START  16384
#define OFF_CURSOR 33024
#define OFF_S2F4   65536
#define OFF_S2J    1114112
#define OFF_S1F4   1376256
#define OFF_S1Q    2424832
#define WS_NEED    2686976

// ---------------- k_zero: zero bucket counters ------------------------------
__global__ __launch_bounds__(256) void k_zero(unsigned* __restrict__ cnt) {
    const int i = blockIdx.x * 256 + threadIdx.x;   // grid 16*256 = 4096
    cnt[i] = 0u;
}

// ---------------- k_hist: count points per bucket ---------------------------
__global__ __launch_bounds__(256) void k_hist(const float* __restrict__ pc1,
                                              const float* __restrict__ pc2,
                                              unsigned* __restrict__ cnt) {
    const int gt = blockIdx.x * 256 + threadIdx.x;  // 0..131071
    const int which = gt >> 16;                     // 0 = pc1, 1 = pc2
    const int r = gt & 65535;
    const int b = r >> 13;
    const int i = r & (N - 1);
    const float* p = which ? pc2 : pc1;
    const float x = p[(size_t)b * 3 * N + i];
    atomicAdd(&cnt[(which * BATCH + b) * NB + bucketOf(x)], 1u);
}

// ---------------- k_scan: per-(which,b) exclusive scan of 256 counts --------
__global__ __launch_bounds__(256) void k_scan(const unsigned* __restrict__ cnt,
                                              unsigned* __restrict__ start,
                                              unsigned* __restrict__ cursor) {
    __shared__ unsigned sbuf[NB];
    const int wb = blockIdx.x;         // 0..15 = which*8+b
    const int t  = threadIdx.x;
    const unsigned v = cnt[wb * NB + t];
    sbuf[t] = v;
    __syncthreads();
    for (int off = 1; off < NB; off <<= 1) {
        unsigned add = (t >= off) ? sbuf[t - off] : 0u;
        __syncthreads();
        sbuf[t] += add;
        __syncthreads();
    }
    const unsigned ex = sbuf[t] - v;   // exclusive
    start[wb * (NB + 1) + t] = ex;
    cursor[wb * NB + t] = ex;
    if (t == NB - 1) start[wb * (NB + 1) + NB] = sbuf[NB - 1];
}

// ---------------- k_scatter: counting-sort scatter with replicated sq -------
__global__ __launch_bounds__(256) void k_scatter(const float* __restrict__ pc1,
                                                 const float* __restrict__ pc2,
                                                 unsigned* __restrict__ cursor,
                                                 float4* __restrict__ s1f4,
                                                 int* __restrict__ s1q,
                                                 float4* __restrict__ s2f4,
                                                 int* __restrict__ s2j) {
#pragma clang fp contract(off)
    const int gt = blockIdx.x * 256 + threadIdx.x;  // 0..131071
    const int which = gt >> 16;
    const int r = gt & 65535;
    const int b = r >> 13;
    const int i = r & (N - 1);
    const float* p = (which ? pc2 : pc1) + (size_t)b * 3 * N;
    const float x = p[i];
    const float y = p[N + i];
    const float z = p[2 * N + i];
    const float xx = x * x;
    const float yy = y * y;
    const float zz = z * z;
    const float sq = (xx + yy) + zz;                // replicated, no FMA
    const int bkt = bucketOf(x);
    const unsigned slot = atomicAdd(&cursor[(which * BATCH + b) * NB + bkt], 1u);
    const size_t o = ((size_t)b << 13) + slot;
    if (which) { s2f4[o] = make_float4(x, y, z, sq); s2j[o] = i; }
    else       { s1f4[o] = make_float4(x, y, z, sq); s1q[o] = i; }
}

// ---------------- k_nn: outward bucket walk, exact lex-min ------------------
__global__ __launch_bounds__(64) void k_nn(const float4* __restrict__ s1f4,
                                           const int* __restrict__ s1q,
                                           const float4* __restrict__ s2f4,
                                           const int* __restrict__ s2j,
                                           const unsigned* __restrict__ start,
                                           const float* __restrict__ pc2,
                                           float* __restrict__ flow) {
#pragma clang fp contract(off)
    const int g = blockIdx.x * 64 + threadIdx.x;    // 0..65535 (sorted order)
    const int b = g >> 13;
    const float4 q = s1f4[g];
    const unsigned oq = (unsigned)s1q[g];
    const unsigned* st = start + (size_t)(BATCH + b) * (NB + 1);  // which=1 region
    const float4* cf = s2f4 + ((size_t)b << 13);
    const int*    cj = s2j  + ((size_t)b << 13);

    float    best = FLT_MAX;
    unsigned bj   = 0u;

    auto upd = [&](float d2, unsigned j) {
        const bool c = (d2 < best) || (d2 == best && j < bj);
        bj   = c ? j  : bj;
        best = c ? d2 : best;
    };
    auto dist = [&](float4 c) -> float {
        const float t0 = q.x * c.x;            // rounded mul
        const float t1 = fmaf(q.y, c.y, t0);
        const float t2 = fmaf(q.z, c.z, t1);
        const float ss = q.w + c.w;            // (sq1+sq2) rounded
        return fmaf(t2, -2.0f, ss);            // == ss - 2*t2 bit-exactly
    };
    auto proc = [&](int k) {
        unsigned i0 = st[k], i1 = st[k + 1];
        unsigned i = i0;
        for (; i + 4 <= i1; i += 4) {          // 4-wide ILP chunk
            const float4 c0 = cf[i], c1 = cf[i + 1], c2 = cf[i + 2], c3 = cf[i + 3];
            const unsigned j0 = (unsigned)cj[i],     j1 = (unsigned)cj[i + 1];
            const unsigned j2 = (unsigned)cj[i + 2], j3 = (unsigned)cj[i + 3];
            const float d0 = dist(c0), d1 = dist(c1), d2_ = dist(c2), d3 = dist(c3);
            upd(d0, j0); upd(d1, j1); upd(d2_, j2); upd(d3, j3);
        }
        for (; i < i1; ++i) upd(dist(cf[i]), (unsigned)cj[i]);
    };

    const int cb = bucketOf(q.x);
    proc(cb);
    int l = cb - 1, rr = cb + 1;
    for (;;) {
        bool ar = false, al = false;
        if (rr <= NB - 1) {
            const float d = fmaf((float)rr, BH, XMINB) - q.x;   // left edge of rr
            ar = (d * d <= best + MARGIN);
        }
        if (l >= 0) {
            const float d = q.x - fmaf((float)(l + 1), BH, XMINB); // right edge of l
            al = (d * d <= best + MARGIN);
        }
        if (!ar && !al) break;
        if (ar) { proc(rr); ++rr; }
        if (al) { proc(l);  --l;  }
    }

    // gather winner coords, scatter flow to original position
    const float* p2b = pc2 + (size_t)b * 3 * N;
    float* fo = flow + (size_t)b * 3 * N;
    fo[oq]         = p2b[bj]         - q.x;
    fo[N + oq]     = p2b[N + bj]     - q.y;
    fo[2 * N + oq] = p2b[2 * N + bj] - q.z;
}

// ---------------- fallback: monolithic brute force (no workspace) -----------
__global__ __launch_bounds__(256) void knn_mono(const float* __restrict__ pc1,
                                                const float* __restrict__ pc2,
                                                float* __restrict__ flow) {
#pragma clang fp contract(off)
    constexpr int TILE = 1024;
    __shared__ float4 tile[TILE];
    const int t = threadIdx.x;
    const int g = blockIdx.x * 256 + t;
    const int b = g >> 13;
    const int q = g & (N - 1);
    const float* p1b = pc1 + (size_t)b * 3 * N;
    const float* p2b = pc2 + (size_t)b * 3 * N;
    const float x1 = p1b[q], y1 = p1b[N + q], z1 = p1b[2 * N + q];
    const float sq1 = (x1 * x1 + y1 * y1) + z1 * z1;
    float best = FLT_MAX;
    int   bi   = 0;
    for (int s = 0; s < N / TILE; ++s) {
        __syncthreads();
        for (int j = t; j < TILE; j += 256) {
            const int jj = s * TILE + j;
            const float x = p2b[jj], y = p2b[N + jj], z = p2b[2 * N + jj];
            tile[j] = make_float4(x, y, z, (x * x + y * y) + z * z);
        }
        __syncthreads();
        #pragma unroll 4
        for (int j = 0; j < TILE; ++j) {
            const float4 c = tile[j];
            const float t0 = x1 * c.x;
            const float t1 = fmaf(y1, c.y, t0);
            const float t2 = fmaf(z1, c.z, t1);
            const float ss = sq1 + c.w;
            const float d2 = fmaf(t2, -2.0f, ss);
            const bool  lt = d2 < best;
            best = lt ? d2 : best;
            bi   = lt ? s * TILE + j : bi;
        }
    }
    float* fo = flow + (size_t)b * 3 * N;
    fo[q]         = p2b[bi]         - x1;
    fo[N + q]     = p2b[N + bi]     - y1;
    fo[2 * N + q] = p2b[2 * N + bi] - z1;
}

extern "C" void kernel_launch(void* const* d_in, const int* in_sizes, int n_in,
                              void* d_out, int out_size, void* d_ws, size_t ws_size,
                              hipStream_t stream) {
    const float* pc1 = (const float*)d_in[0];
    const float* pc2 = (const float*)d_in[1];
    float* flow = (float*)d_out;

    if (ws_size >= WS_NEED) {
        char* base = (char*)d_ws;
        unsigned* cnt    = (unsigned*)(base + OFF_CNT);
        unsigned* start  = (unsigned*)(base + OFF_START);
        unsigned* cursor = (unsigned*)(base + OFF_CURSOR);
        float4*   s2f4   = (float4*)(base + OFF_S2F4);
        int*      s2j    = (int*)(base + OFF_S2J);
        float4*   s1f4   = (float4*)(base + OFF_S1F4);
        int*      s1q    = (int*)(base + OFF_S1Q);

        k_zero<<<16, 256, 0, stream>>>(cnt);
        k_hist<<<512, 256, 0, stream>>>(pc1, pc2, cnt);
        k_scan<<<16, 256, 0, stream>>>(cnt, start, cursor);
        k_scatter<<<512, 256, 0, stream>>>(pc1, pc2, cursor, s1f4, s1q, s2f4, s2j);
        k_nn<<<1024, 64, 0, stream>>>(s1f4, s1q, s2f4, s2j, start, pc2, flow);
    } else {
        knn_mono<<<(BATCH * N) / 256, 256, 0, stream>>>(pc1, pc2, flow);
    }
}

// Round 5
// 446.886 us; speedup vs baseline: 1.8793x; 1.8793x over previous
//
#include <hip/hip_runtime.h>
#include <float.h>

// knnFlow: pc1 [B,3,N] f32, pc2 [B,3,N] f32 -> flow [B,3,N] f32
// Bit-replicates the reference's f32 Gram expansion (absmax 0.0 verified R2-R4):
//   sq = (x*x + y*y) + z*z               (plain rounded ops, no FMA)
//   t0 = x1*x2; t1 = fmaf(y1,y2,t0); t2 = fmaf(z1,z2,t1)
//   d2 = fmaf(t2, -2.0f, sq1+sq2)        (== (sq1+sq2) - 2*gram bit-exactly)
// argmin = lexicographic min over (d2, orig_j) == np.argmin first-occurrence.
//
// Sorted-window search: counting-sort both clouds by x (256 buckets). One block
// = 64 consecutive sorted queries x 2 waves. Block walks the sorted candidate
// array outward with pointers, staging 256-candidate chunks into LDS
// (coalesced), scanning via wave-uniform LDS broadcast (R3's proven pattern).
// A side stops when its next bucket-edge dx^2 > best+MARGIN for ALL lanes.
// MARGIN 2e-3 >> 1e-4 worst-case rounding => every candidate tied-or-better
// than the final best is provably scanned => lex-min is exact and
// deterministic (independent of the nondeterministic intra-bucket order).

#define BATCH 8
#define N     8192
#define NB    256
#define XMINB (-5.12f)
#define BH    (0.04f)
#define INVH  (25.0f)
#define MARGIN (2.0e-3f)
#define CH    256       // staged candidates per side per iteration
#define BLKN  128       // 2 waves: same 64 queries, candidate-parity split

__device__ __forceinline__ int bucketOf(float x) {
    int k = (int)floorf((x - XMINB) * INVH);
    return k < 0 ? 0 : (k > NB - 1 ? NB - 1 : k);
}

// ws layout (bytes) — proven to fit in R4:
#define OFF_CNT    0         // cnt   [2][B][NB]   u32   (16384)
#define OFF_START  16384     // start [2][B][NB+1] u32   (16448)
#define OFF_CURSOR 33024     // cursor[2][B][NB]   u32   (16384)
#define OFF_S2F4   65536     // s2f4  [B][N] float4      (1048576)
#define OFF_S2J    1114112   // s2j   [B][N] int         (262144)
#define OFF_S1F4   1376256   // s1f4  [B][N] float4      (1048576)
#define OFF_S1Q    2424832   // s1q   [B][N] int         (262144)
#define WS_NEED    2686976

// ---------------- k_zero -----------------------------------------------------
__global__ __launch_bounds__(256) void k_zero(unsigned* __restrict__ cnt) {
    cnt[blockIdx.x * 256 + threadIdx.x] = 0u;   // grid 16 -> 4096 counters
}

// ---------------- k_hist -----------------------------------------------------
__global__ __launch_bounds__(256) void k_hist(const float* __restrict__ pc1,
                                              const float* __restrict__ pc2,
                                              unsigned* __restrict__ cnt) {
    const int gt = blockIdx.x * 256 + threadIdx.x;  // 0..131071
    const int which = gt >> 16;
    const int r = gt & 65535;
    const int b = r >> 13;
    const int i = r & (N - 1);
    const float* p = which ? pc2 : pc1;
    const float x = p[(size_t)b * 3 * N + i];
    atomicAdd(&cnt[(which * BATCH + b) * NB + bucketOf(x)], 1u);
}

// ---------------- k_scan -----------------------------------------------------
__global__ __launch_bounds__(256) void k_scan(const unsigned* __restrict__ cnt,
                                              unsigned* __restrict__ start,
                                              unsigned* __restrict__ cursor) {
    __shared__ unsigned sbuf[NB];
    const int wb = blockIdx.x;         // 0..15 = which*8+b
    const int t  = threadIdx.x;
    const unsigned v = cnt[wb * NB + t];
    sbuf[t] = v;
    __syncthreads();
    for (int off = 1; off < NB; off <<= 1) {
        unsigned add = (t >= off) ? sbuf[t - off] : 0u;
        __syncthreads();
        sbuf[t] += add;
        __syncthreads();
    }
    const unsigned ex = sbuf[t] - v;
    start[wb * (NB + 1) + t] = ex;
    cursor[wb * NB + t] = ex;
    if (t == NB - 1) start[wb * (NB + 1) + NB] = sbuf[NB - 1];
}

// ---------------- k_scatter --------------------------------------------------
__global__ __launch_bounds__(256) void k_scatter(const float* __restrict__ pc1,
                                                 const float* __restrict__ pc2,
                                                 unsigned* __restrict__ cursor,
                                                 float4* __restrict__ s1f4,
                                                 int* __restrict__ s1q,
                                                 float4* __restrict__ s2f4,
                                                 int* __restrict__ s2j) {
#pragma clang fp contract(off)
    const int gt = blockIdx.x * 256 + threadIdx.x;  // 0..131071
    const int which = gt >> 16;
    const int r = gt & 65535;
    const int b = r >> 13;
    const int i = r & (N - 1);
    const float* p = (which ? pc2 : pc1) + (size_t)b * 3 * N;
    const float x = p[i];
    const float y = p[N + i];
    const float z = p[2 * N + i];
    const float xx = x * x;
    const float yy = y * y;
    const float zz = z * z;
    const float sq = (xx + yy) + zz;                // replicated, no FMA
    const int bkt = bucketOf(x);
    const unsigned slot = atomicAdd(&cursor[(which * BATCH + b) * NB + bkt], 1u);
    const size_t o = ((size_t)b << 13) + slot;
    if (which) { s2f4[o] = make_float4(x, y, z, sq); s2j[o] = i; }
    else       { s1f4[o] = make_float4(x, y, z, sq); s1q[o] = i; }
}

// ---------------- k_nn2: block-collective sorted-window scan -----------------
__global__ __launch_bounds__(BLKN) void k_nn2(const float4* __restrict__ s1f4,
                                              const int* __restrict__ s1q,
                                              const float4* __restrict__ s2f4,
                                              const int* __restrict__ s2j,
                                              const unsigned* __restrict__ start,
                                              const float* __restrict__ pc2,
                                              float* __restrict__ flow) {
#pragma clang fp contract(off)
    __shared__ float4   stg[2 * CH];
    __shared__ int      stj[2 * CH];
    __shared__ unsigned stl[NB + 1];
    __shared__ int      flags[2];
    __shared__ float    shb[BLKN];
    __shared__ unsigned shj[BLKN];

    const int t    = threadIdx.x;
    const int lane = t & 63;
    const int h    = t >> 6;               // candidate-parity half (wave id)
    const int bid  = blockIdx.x;
    const int b    = bid >> 7;             // batch (128 blocks per batch)
    const int qlo  = (bid & 127) * 64;
    const size_t sbase = (size_t)b << 13;
    const float4* cf  = s2f4 + sbase;
    const int*    cjA = s2j  + sbase;

    for (int i = t; i < NB + 1; i += BLKN)
        stl[i] = start[(size_t)(BATCH + b) * (NB + 1) + i];

    const float4  q  = s1f4[sbase + qlo + lane];   // this lane's query (both waves)
    const unsigned oq = (unsigned)s1q[sbase + qlo + lane];
    __syncthreads();

    const int cb = bucketOf(s1f4[sbase + qlo + 32].x);   // block-median center
    int rptr = (int)stl[cb], lptr = (int)stl[cb];
    int rbkt = cb, lb = cb;

    float    b0 = FLT_MAX, b1 = FLT_MAX, b2 = FLT_MAX, b3 = FLT_MAX;
    unsigned j0 = 0u, j1 = 0u, j2 = 0u, j3 = 0u;

    auto body = [&](int idx, float& bb, unsigned& jb) {
        const float4  c = stg[idx];               // wave-uniform -> broadcast
        const unsigned j = (unsigned)stj[idx];
        const float t0 = q.x * c.x;               // rounded mul (contract off)
        const float t1 = fmaf(q.y, c.y, t0);
        const float t2 = fmaf(q.z, c.z, t1);
        const float ss = q.w + c.w;
        const float d  = fmaf(t2, -2.0f, ss);     // == ss - 2*t2 bit-exactly
        const bool cc = (d < bb) || (d == bb && j < jb);  // lex-min (d2, orig j)
        jb = cc ? j : jb;
        bb = cc ? d : bb;
    };
    auto scan = [&](int lo, int hi) {             // wave h takes parity-h slots
        int j = lo + h;
        for (; j + 8 <= hi; j += 8) {             // 4 independent acc chains
            body(j,     b0, j0); body(j + 2, b1, j1);
            body(j + 4, b2, j2); body(j + 6, b3, j3);
        }
        for (; j < hi; j += 2) body(j, b0, j0);
    };

    for (;;) {
        while (rbkt < NB - 1 && rptr >= (int)stl[rbkt + 1]) ++rbkt;
        while (lb > 0 && lptr - 1 < (int)stl[lb]) --lb;
        const float bmin = fminf(fminf(b0, b1), fminf(b2, b3));
        const float lim  = bmin + MARGIN;
        bool my_r = false, my_l = false;
        if (rptr < N) {   // bucket 0's left edge is effectively -inf
            const float e  = (rbkt <= 0) ? -FLT_MAX : fmaf((float)rbkt, BH, XMINB);
            const float dx = e - q.x;
            my_r = (dx <= 0.0f) || (dx * dx <= lim);
        }
        if (lptr > 0) {   // bucket 255's right edge is effectively +inf
            const float e  = (lb >= NB - 1) ? FLT_MAX : fmaf((float)(lb + 1), BH, XMINB);
            const float dx = q.x - e;
            my_l = (dx <= 0.0f) || (dx * dx <= lim);
        }
        if (t == 0) { flags[0] = 0; flags[1] = 0; }
        __syncthreads();
        if (my_r) flags[0] = 1;
        if (my_l) flags[1] = 1;
        __syncthreads();
        const bool nr = flags[0] != 0;
        const bool nl = flags[1] != 0;
        if (!nr && !nl) break;
        const int cr = nr ? min(CH, N - rptr) : 0;
        const int cl = nl ? min(CH, lptr) : 0;
        for (int i = t; i < cr; i += BLKN) {      // coalesced global -> LDS
            stg[i] = cf[rptr + i];  stj[i] = cjA[rptr + i];
        }
        for (int i = t; i < cl; i += BLKN) {
            stg[CH + i] = cf[lptr - cl + i];  stj[CH + i] = cjA[lptr - cl + i];
        }
        __syncthreads();
        scan(0, cr);
        scan(CH, CH + cl);
        rptr += cr;  lptr -= cl;
        __syncthreads();
    }

    // merge 4 accumulators, then the two wave halves; wave 0 writes output
    auto lexm = [](float db, unsigned jb, float& B, unsigned& J) {
        const bool cc = (db < B) || (db == B && jb < J);
        J = cc ? jb : J;  B = cc ? db : B;
    };
    float B = b0; unsigned J = j0;
    lexm(b1, j1, B, J); lexm(b2, j2, B, J); lexm(b3, j3, B, J);
    shb[t] = B; shj[t] = J;
    __syncthreads();
    if (t < 64) {
        lexm(shb[t + 64], shj[t + 64], B, J);
        const float* p2b = pc2 + (size_t)b * 3 * N;
        float* fo = flow + (size_t)b * 3 * N;
        fo[oq]         = p2b[J]         - q.x;
        fo[N + oq]     = p2b[N + J]     - q.y;
        fo[2 * N + oq] = p2b[2 * N + J] - q.z;
    }
}

// ---------------- fallback: monolithic brute force (no workspace) -----------
__global__ __launch_bounds__(256) void knn_mono(const float* __restrict__ pc1,
                                                const float* __restrict__ pc2,
                                                float* __restrict__ flow) {
#pragma clang fp contract(off)
    constexpr int TILE = 1024;
    __shared__ float4 tile[TILE];
    const int t = threadIdx.x;
    const int g = blockIdx.x * 256 + t;
    const int b = g >> 13;
    const int q = g & (N - 1);
    const float* p1b = pc1 + (size_t)b * 3 * N;
    const float* p2b = pc2 + (size_t)b * 3 * N;
    const float x1 = p1b[q], y1 = p1b[N + q], z1 = p1b[2 * N + q];
    const float sq1 = (x1 * x1 + y1 * y1) + z1 * z1;
    float best = FLT_MAX;
    int   bi   = 0;
    for (int s = 0; s < N / TILE; ++s) {
        __syncthreads();
        for (int j = t; j < TILE; j += 256) {
            const int jj = s * TILE + j;
            const float x = p2b[jj], y = p2b[N + jj], z = p2b[2 * N + jj];
            tile[j] = make_float4(x, y, z, (x * x + y * y) + z * z);
        }
        __syncthreads();
        #pragma unroll 4
        for (int j = 0; j < TILE; ++j) {
            const float4 c = tile[j];
            const float t0 = x1 * c.x;
            const float t1 = fmaf(y1, c.y, t0);
            const float t2 = fmaf(z1, c.z, t1);
            const float ss = sq1 + c.w;
            const float d2 = fmaf(t2, -2.0f, ss);
            const bool  lt = d2 < best;
            best = lt ? d2 : best;
            bi   = lt ? s * TILE + j : bi;
        }
    }
    float* fo = flow + (size_t)b * 3 * N;
    fo[q]         = p2b[bi]         - x1;
    fo[N + q]     = p2b[N + bi]     - y1;
    fo[2 * N + q] = p2b[2 * N + bi] - z1;
}

extern "C" void kernel_launch(void* const* d_in, const int* in_sizes, int n_in,
                              void* d_out, int out_size, void* d_ws, size_t ws_size,
                              hipStream_t stream) {
    const float* pc1 = (const float*)d_in[0];
    const float* pc2 = (const float*)d_in[1];
    float* flow = (float*)d_out;

    if (ws_size >= WS_NEED) {
        char* base = (char*)d_ws;
        unsigned* cnt    = (unsigned*)(base + OFF_CNT);
        unsigned* start  = (unsigned*)(base + OFF_START);
        unsigned* cursor = (unsigned*)(base + OFF_CURSOR);
        float4*   s2f4   = (float4*)(base + OFF_S2F4);
        int*      s2j    = (int*)(base + OFF_S2J);
        float4*   s1f4   = (float4*)(base + OFF_S1F4);
        int*      s1q    = (int*)(base + OFF_S1Q);

        k_zero<<<16, 256, 0, stream>>>(cnt);
        k_hist<<<512, 256, 0, stream>>>(pc1, pc2, cnt);
        k_scan<<<16, 256, 0, stream>>>(cnt, start, cursor);
        k_scatter<<<512, 256, 0, stream>>>(pc1, pc2, cursor, s1f4, s1q, s2f4, s2j);
        k_nn2<<<BATCH * 128, BLKN, 0, stream>>>(s1f4, s1q, s2f4, s2j, start, pc2, flow);
    } else {
        knn_mono<<<(BATCH * N) / 256, 256, 0, stream>>>(pc1, pc2, flow);
    }
}

// Round 6
// 305.881 us; speedup vs baseline: 2.7456x; 1.4610x over previous
//
#include <hip/hip_runtime.h>
#include <float.h>

// knnFlow: pc1 [B,3,N] f32, pc2 [B,3,N] f32 -> flow [B,3,N] f32
// Bit-replicates the reference's f32 Gram expansion (absmax 0.0 verified R2-R5):
//   sq = (x*x + y*y) + z*z               (plain rounded ops, no FMA)
//   t0 = x1*x2; t1 = fmaf(y1,y2,t0); t2 = fmaf(z1,z2,t1)
//   d2 = fmaf(t2, -2.0f, sq1+sq2)        (== (sq1+sq2) - 2*gram bit-exactly)
// argmin = lexicographic min over (d2, orig_j) == np.argmin first-occurrence.
//
// Structure: counting-sort both clouds by x; pass1 scans a STATIC bucket window
// (+-6 buckets = +-0.24) per 256-query block with R3's proven broadcast-scan
// pattern; a reduce kernel verifies each query's result with a conservative
// edge test (margin 1e-3 >> 2e-5 rounding bound) and brute-forces the few
// failures (sparse-tail queries) exactly. No data-dependent voting loops.

#define BATCH 8
#define N     8192
#define NB    256
#define XMINB (-5.12f)
#define BH    (0.04f)
#define INVH  (25.0f)
#define RB    6          // window half-width in buckets (0.24 in x)
#define EPS   (1.0e-3f)  // pass-test margin >> 2e-5 formula-error bound
#define NS1   4          // pass1 candidate splits
#define NSC   4          // cleanup candidate splits
#define CAP   512        // staged candidates per LDS chunk

__device__ __forceinline__ int bucketOf(float x) {
    int k = (int)floorf((x - XMINB) * INVH);
    return k < 0 ? 0 : (k > NB - 1 ? NB - 1 : k);
}

// ws layout (bytes):
#define OFF_CNT    0         // cnt    [2][B][NB]   u32    (16384)
#define OFF_START  16384     // start  [2][B][NB+1] u32    (16448)
#define OFF_CURSOR 33024     // cursor [2][B][NB]   u32    (16384) -> 49408
#define OFF_FCNT   49408     // fcnt   [B] u32             (32)
#define OFF_FLIST  49664     // flist  [B][N] u32          (262144) -> 311808
#define OFF_S2F4   311808    // s2f4   [B][N] float4       (1048576)
#define OFF_S2J    1360384   // s2j    [B][N] int          (262144)
#define OFF_S1F4   1622528   // s1f4   [B][N] float4       (1048576)
#define OFF_S1Q    2671104   // s1q    [B][N] int          (262144)
#define OFF_PART   2933248   // part1 / clnpart [4][B*N] uint2 (2097152, aliased)
#define WS_NEED    5030400

// ---------------- k_zero: counters + fail counts -----------------------------
__global__ __launch_bounds__(256) void k_zero(unsigned* __restrict__ cnt,
                                              unsigned* __restrict__ fcnt) {
    const int i = blockIdx.x * 256 + threadIdx.x;   // grid 17 -> 4352 >= 4104
    if (i < 4096) cnt[i] = 0u;
    else if (i < 4096 + BATCH) fcnt[i - 4096] = 0u;
}

// ---------------- k_hist -----------------------------------------------------
__global__ __launch_bounds__(256) void k_hist(const float* __restrict__ pc1,
                                              const float* __restrict__ pc2,
                                              unsigned* __restrict__ cnt) {
    const int gt = blockIdx.x * 256 + threadIdx.x;  // 0..131071
    const int which = gt >> 16;
    const int r = gt & 65535;
    const int b = r >> 13;
    const int i = r & (N - 1);
    const float* p = which ? pc2 : pc1;
    const float x = p[(size_t)b * 3 * N + i];
    atomicAdd(&cnt[(which * BATCH + b) * NB + bucketOf(x)], 1u);
}

// ---------------- k_scan -----------------------------------------------------
__global__ __launch_bounds__(256) void k_scan(const unsigned* __restrict__ cnt,
                                              unsigned* __restrict__ start,
                                              unsigned* __restrict__ cursor) {
    __shared__ unsigned sbuf[NB];
    const int wb = blockIdx.x;         // 0..15 = which*8+b
    const int t  = threadIdx.x;
    const unsigned v = cnt[wb * NB + t];
    sbuf[t] = v;
    __syncthreads();
    for (int off = 1; off < NB; off <<= 1) {
        unsigned add = (t >= off) ? sbuf[t - off] : 0u;
        __syncthreads();
        sbuf[t] += add;
        __syncthreads();
    }
    const unsigned ex = sbuf[t] - v;
    start[wb * (NB + 1) + t] = ex;
    cursor[wb * NB + t] = ex;
    if (t == NB - 1) start[wb * (NB + 1) + NB] = sbuf[NB - 1];
}

// ---------------- k_scatter --------------------------------------------------
__global__ __launch_bounds__(256) void k_scatter(const float* __restrict__ pc1,
                                                 const float* __restrict__ pc2,
                                                 unsigned* __restrict__ cursor,
                                                 float4* __restrict__ s1f4,
                                                 int* __restrict__ s1q,
                                                 float4* __restrict__ s2f4,
                                                 int* __restrict__ s2j) {
#pragma clang fp contract(off)
    const int gt = blockIdx.x * 256 + threadIdx.x;  // 0..131071
    const int which = gt >> 16;
    const int r = gt & 65535;
    const int b = r >> 13;
    const int i = r & (N - 1);
    const float* p = (which ? pc2 : pc1) + (size_t)b * 3 * N;
    const float x = p[i];
    const float y = p[N + i];
    const float z = p[2 * N + i];
    const float xx = x * x;
    const float yy = y * y;
    const float zz = z * z;
    const float sq = (xx + yy) + zz;                // replicated, no FMA
    const int bkt = bucketOf(x);
    const unsigned slot = atomicAdd(&cursor[(which * BATCH + b) * NB + bkt], 1u);
    const size_t o = ((size_t)b << 13) + slot;
    if (which) { s2f4[o] = make_float4(x, y, z, sq); s2j[o] = i; }
    else       { s1f4[o] = make_float4(x, y, z, sq); s1q[o] = i; }
}

// shared scan body: exact ref distance + lex-min update
#define BODY(K, BB, JB) {                                                   \
    const float4  c = stg[(K)];                                             \
    const unsigned jj = (unsigned)stj[(K)];                                 \
    const float t0 = q.x * c.x;                                             \
    const float t1 = fmaf(q.y, c.y, t0);                                    \
    const float t2 = fmaf(q.z, c.z, t1);                                    \
    const float ss = q.w + c.w;                                             \
    const float d  = fmaf(t2, -2.0f, ss);                                   \
    const bool cc = (d < (BB)) || (d == (BB) && jj < (JB));                 \
    (JB) = cc ? jj : (JB);  (BB) = cc ? d : (BB);                           \
}

// ---------------- k_pass1: static bucket-window scan -------------------------
__global__ __launch_bounds__(256) void k_pass1(const float4* __restrict__ s1f4,
                                               const float4* __restrict__ s2f4,
                                               const int* __restrict__ s2j,
                                               const unsigned* __restrict__ start,
                                               uint2* __restrict__ part1) {
#pragma clang fp contract(off)
    __shared__ float4 stg[CAP];
    __shared__ int    stj[CAP];
    const int t = threadIdx.x;
    const int g = blockIdx.x;              // 0..31 query-block within batch
    const int s = blockIdx.y;              // 0..NS1-1
    const int b = blockIdx.z;              // 0..7
    const size_t qb = (size_t)b << 13;
    const unsigned* stl = start + (size_t)(BATCH + b) * (NB + 1);

    const float4 q = s1f4[qb + g * 256 + t];
    const float xf = s1f4[qb + g * 256].x;       // block-min bucket rep
    const float xl = s1f4[qb + g * 256 + 255].x; // block-max bucket rep
    int blo = bucketOf(xf) - RB; if (blo < 0) blo = 0;
    int bhi = bucketOf(xl) + RB; if (bhi > NB - 1) bhi = NB - 1;
    const int lo = (int)stl[blo], hi = (int)stl[bhi + 1];
    const int len = hi - lo;
    const int slo = lo + (len * s) / NS1;        // block-uniform slice
    const int shi = lo + (len * (s + 1)) / NS1;

    const float4* cf = s2f4 + qb;
    const int*    cj = s2j + qb;
    float    b0 = FLT_MAX, b1 = FLT_MAX, b2 = FLT_MAX, b3 = FLT_MAX;
    unsigned j0 = ~0u, j1 = ~0u, j2 = ~0u, j3 = ~0u;

    for (int c0 = slo; c0 < shi; c0 += CAP) {
        const int cnt = min(CAP, shi - c0);
        __syncthreads();
        for (int i = t; i < cnt; i += 256) { stg[i] = cf[c0 + i]; stj[i] = cj[c0 + i]; }
        __syncthreads();
        int k = 0;
        for (; k + 4 <= cnt; k += 4) {           // 4 independent lex-min chains
            BODY(k, b0, j0); BODY(k + 1, b1, j1);
            BODY(k + 2, b2, j2); BODY(k + 3, b3, j3);
        }
        for (; k < cnt; ++k) BODY(k, b0, j0);
    }
    // merge 4 accumulators (lex)
    bool c;
    c = (b1 < b0) || (b1 == b0 && j1 < j0); b0 = c ? b1 : b0; j0 = c ? j1 : j0;
    c = (b3 < b2) || (b3 == b2 && j3 < j2); b2 = c ? b3 : b2; j2 = c ? j3 : j2;
    c = (b2 < b0) || (b2 == b0 && j2 < j0); b0 = c ? b2 : b0; j0 = c ? j2 : j0;
    part1[(size_t)s * (BATCH * N) + qb + g * 256 + t] = make_uint2(__float_as_uint(b0), j0);
}

// ---------------- k_p1red: merge, verify, write or defer ---------------------
__global__ __launch_bounds__(256) void k_p1red(const float4* __restrict__ s1f4,
                                               const int* __restrict__ s1q,
                                               const float* __restrict__ pc2,
                                               const uint2* __restrict__ part1,
                                               const unsigned* __restrict__ start,
                                               unsigned* __restrict__ fcnt,
                                               unsigned* __restrict__ flist,
                                               float* __restrict__ flow) {
#pragma clang fp contract(off)
    const int gpos = blockIdx.x * 256 + threadIdx.x;   // 0..65535
    const int b = gpos >> 13;
    const int p = gpos & (N - 1);

    float best = FLT_MAX; unsigned bj = ~0u;
    #pragma unroll
    for (int s = 0; s < NS1; ++s) {
        const uint2 pr = part1[(size_t)s * (BATCH * N) + gpos];
        const float d = __uint_as_float(pr.x);
        const bool cc = (d < best) || (d == best && pr.y < bj);
        bj = cc ? pr.y : bj;  best = cc ? d : best;
    }

    // recompute window bounds exactly as k_pass1
    const int g = p >> 8;
    const size_t qb = (size_t)b << 13;
    const float xf = s1f4[qb + (g << 8)].x;
    const float xl = s1f4[qb + (g << 8) + 255].x;
    int blo = bucketOf(xf) - RB; if (blo < 0) blo = 0;
    int bhi = bucketOf(xl) + RB; if (bhi > NB - 1) bhi = NB - 1;

    const float4 q = s1f4[gpos];
    bool pass = true;
    if (blo > 0) {
        const float dL = q.x - (XMINB + (float)blo * BH);
        pass = pass && (dL * dL >= best + EPS);
    }
    if (bhi < NB - 1) {
        const float dR = (XMINB + (float)(bhi + 1) * BH) - q.x;
        pass = pass && (dR * dR >= best + EPS);
    }

    if (pass) {
        const unsigned oq = (unsigned)s1q[gpos];
        const float* p2b = pc2 + (size_t)b * 3 * N;
        float* fo = flow + (size_t)b * 3 * N;
        fo[oq]         = p2b[bj]         - q.x;
        fo[N + oq]     = p2b[N + bj]     - q.y;
        fo[2 * N + oq] = p2b[2 * N + bj] - q.z;
    } else {
        const unsigned fi = atomicAdd(&fcnt[b], 1u);
        flist[qb + fi] = (unsigned)p;
    }
}

// ---------------- k_cln: brute-force failed queries (partials) ---------------
__global__ __launch_bounds__(256) void k_cln(const float4* __restrict__ s1f4,
                                             const float4* __restrict__ s2f4,
                                             const int* __restrict__ s2j,
                                             const unsigned* __restrict__ fcnt,
                                             const unsigned* __restrict__ flist,
                                             uint2* __restrict__ clnpart) {
#pragma clang fp contract(off)
    __shared__ float4 stg[CAP];
    __shared__ int    stj[CAP];
    const int t = threadIdx.x;
    const int chunk = blockIdx.x;          // 0..31
    const int s = blockIdx.y;              // 0..NSC-1
    const int b = blockIdx.z;
    const unsigned F = fcnt[b];
    if ((unsigned)(chunk * 256) >= F) return;   // whole-block uniform exit

    const size_t qb = (size_t)b << 13;
    const int f = chunk * 256 + t;
    const bool active = (unsigned)f < F;
    const unsigned p = active ? flist[qb + f] : 0u;
    const float4 q = s1f4[qb + p];

    const float4* cf = s2f4 + qb;
    const int*    cj = s2j + qb;
    const int slo = s * (N / NSC), shi = slo + (N / NSC);

    float    b0 = FLT_MAX, b1 = FLT_MAX;
    unsigned j0 = ~0u, j1 = ~0u;
    for (int c0 = slo; c0 < shi; c0 += CAP) {
        __syncthreads();
        for (int i = t; i < CAP; i += 256) { stg[i] = cf[c0 + i]; stj[i] = cj[c0 + i]; }
        __syncthreads();
        for (int k = 0; k < CAP; k += 2) { BODY(k, b0, j0); BODY(k + 1, b1, j1); }
    }
    const bool c = (b1 < b0) || (b1 == b0 && j1 < j0);
    b0 = c ? b1 : b0; j0 = c ? j1 : j0;
    if (active) clnpart[(size_t)s * (BATCH * N) + qb + f] = make_uint2(__float_as_uint(b0), j0);
}

// ---------------- k_clnred: merge cleanup partials, write flow ---------------
__global__ __launch_bounds__(256) void k_clnred(const float4* __restrict__ s1f4,
                                                const int* __restrict__ s1q,
                                                const float* __restrict__ pc2,
                                                const uint2* __restrict__ clnpart,
                                                const unsigned* __restrict__ fcnt,
                                                const unsigned* __restrict__ flist,
                                                float* __restrict__ flow) {
    const int b = blockIdx.y;
    const int f = blockIdx.x * 256 + threadIdx.x;
    if ((unsigned)f >= fcnt[b]) return;
    const size_t qb = (size_t)b << 13;
    const unsigned p = flist[qb + f];

    float best = FLT_MAX; unsigned bj = ~0u;
    #pragma unroll
    for (int s = 0; s < NSC; ++s) {
        const uint2 pr = clnpart[(size_t)s * (BATCH * N) + qb + f];
        const float d = __uint_as_float(pr.x);
        const bool cc = (d < best) || (d == best && pr.y < bj);
        bj = cc ? pr.y : bj;  best = cc ? d : best;
    }
    const float4 q = s1f4[qb + p];
    const unsigned oq = (unsigned)s1q[qb + p];
    const float* p2b = pc2 + (size_t)b * 3 * N;
    float* fo = flow + (size_t)b * 3 * N;
    fo[oq]         = p2b[bj]         - q.x;
    fo[N + oq]     = p2b[N + bj]     - q.y;
    fo[2 * N + oq] = p2b[2 * N + bj] - q.z;
}

// ---------------- fallback: monolithic brute force (no workspace) -----------
__global__ __launch_bounds__(256) void knn_mono(const float* __restrict__ pc1,
                                                const float* __restrict__ pc2,
                                                float* __restrict__ flow) {
#pragma clang fp contract(off)
    constexpr int TILE = 1024;
    __shared__ float4 tile[TILE];
    const int t = threadIdx.x;
    const int g = blockIdx.x * 256 + t;
    const int b = g >> 13;
    const int q = g & (N - 1);
    const float* p1b = pc1 + (size_t)b * 3 * N;
    const float* p2b = pc2 + (size_t)b * 3 * N;
    const float x1 = p1b[q], y1 = p1b[N + q], z1 = p1b[2 * N + q];
    const float sq1 = (x1 * x1 + y1 * y1) + z1 * z1;
    float best = FLT_MAX;
    int   bi   = 0;
    for (int s = 0; s < N / TILE; ++s) {
        __syncthreads();
        for (int j = t; j < TILE; j += 256) {
            const int jj = s * TILE + j;
            const float x = p2b[jj], y = p2b[N + jj], z = p2b[2 * N + jj];
            tile[j] = make_float4(x, y, z, (x * x + y * y) + z * z);
        }
        __syncthreads();
        #pragma unroll 4
        for (int j = 0; j < TILE; ++j) {
            const float4 c = tile[j];
            const float t0 = x1 * c.x;
            const float t1 = fmaf(y1, c.y, t0);
            const float t2 = fmaf(z1, c.z, t1);
            const float ss = sq1 + c.w;
            const float d2 = fmaf(t2, -2.0f, ss);
            const bool  lt = d2 < best;
            best = lt ? d2 : best;
            bi   = lt ? s * TILE + j : bi;
        }
    }
    float* fo = flow + (size_t)b * 3 * N;
    fo[q]         = p2b[bi]         - x1;
    fo[N + q]     = p2b[N + bi]     - y1;
    fo[2 * N + q] = p2b[2 * N + bi] - z1;
}

extern "C" void kernel_launch(void* const* d_in, const int* in_sizes, int n_in,
                              void* d_out, int out_size, void* d_ws, size_t ws_size,
                              hipStream_t stream) {
    const float* pc1 = (const float*)d_in[0];
    const float* pc2 = (const float*)d_in[1];
    float* flow = (float*)d_out;

    if (ws_size >= WS_NEED) {
        char* base = (char*)d_ws;
        unsigned* cnt    = (unsigned*)(base + OFF_CNT);
        unsigned* start  = (unsigned*)(base + OFF_START);
        unsigned* cursor = (unsigned*)(base + OFF_CURSOR);
        unsigned* fcnt   = (unsigned*)(base + OFF_FCNT);
        unsigned* flist  = (unsigned*)(base + OFF_FLIST);
        float4*   s2f4   = (float4*)(base + OFF_S2F4);
        int*      s2j    = (int*)(base + OFF_S2J);
        float4*   s1f4   = (float4*)(base + OFF_S1F4);
        int*      s1q    = (int*)(base + OFF_S1Q);
        uint2*    part   = (uint2*)(base + OFF_PART);   // aliased pass1/cleanup

        k_zero<<<17, 256, 0, stream>>>(cnt, fcnt);
        k_hist<<<512, 256, 0, stream>>>(pc1, pc2, cnt);
        k_scan<<<16, 256, 0, stream>>>(cnt, start, cursor);
        k_scatter<<<512, 256, 0, stream>>>(pc1, pc2, cursor, s1f4, s1q, s2f4, s2j);
        k_pass1<<<dim3(32, NS1, BATCH), 256, 0, stream>>>(s1f4, s2f4, s2j, start, part);
        k_p1red<<<256, 256, 0, stream>>>(s1f4, s1q, pc2, part, start, fcnt, flist, flow);
        k_cln<<<dim3(32, NSC, BATCH), 256, 0, stream>>>(s1f4, s2f4, s2j, fcnt, flist, part);
        k_clnred<<<dim3(32, BATCH), 256, 0, stream>>>(s1f4, s1q, pc2, part, fcnt, flist, flow);
    } else {
        knn_mono<<<(BATCH * N) / 256, 256, 0, stream>>>(pc1, pc2, flow);
    }
}